// Round 14
// baseline (279.701 us; speedup 1.0000x reference)
//
#include <hip/hip_runtime.h>
#include <math.h>

#define EMBED 256
#define HEADS 8
#define LEVELS 4
#define POINTS 4
#define FFNDIM 1024

typedef float f32x4 __attribute__((ext_vector_type(4)));
typedef float f32x2 __attribute__((ext_vector_type(2)));
typedef __bf16 bf16x8 __attribute__((ext_vector_type(8)));

static __device__ __forceinline__ float4 ld4f(const float* p) {
    return *reinterpret_cast<const float4*>(p);
}
static __device__ __forceinline__ unsigned short f2bf(float f) {
    unsigned int u = __float_as_uint(f);
    unsigned int r = (u + 0x7fffu + ((u >> 16) & 1u)) >> 16;
    return (unsigned short)r;
}
static __device__ __forceinline__ float bf2f(unsigned short u) {
    return __uint_as_float((unsigned int)u << 16);
}
static __device__ __forceinline__ f32x2 pkfma(f32x2 a, f32x2 b, f32x2 c) {
#if __has_builtin(__builtin_elementwise_fma)
    return __builtin_elementwise_fma(a, b, c);
#else
    f32x2 r; r.x = fmaf(a.x, b.x, c.x); r.y = fmaf(a.y, b.y, c.y); return r;
#endif
}
// async global->LDS, 16B per lane. LDS dest = wave-uniform base + lane*16.
static __device__ __forceinline__
void gl_lds16(const unsigned short* g, unsigned short* l) {
    __builtin_amdgcn_global_load_lds(
        (const __attribute__((address_space(1))) unsigned int*)g,
        (__attribute__((address_space(3))) unsigned int*)l, 16, 0, 0);
}

// ---------------------------------------------------------------------------
// fp32 -> bf16 (RNE) elementwise, vectorized
// ---------------------------------------------------------------------------
__global__ __launch_bounds__(256)
void k_cvt_src(const float* __restrict__ src, unsigned short* __restrict__ dst, int n)
{
    int i = (blockIdx.x * 256 + threadIdx.x) * 4;
    const int stride = gridDim.x * 1024;
    for (; i < n; i += stride) {
        float4 v = ld4f(src + i);
        ushort4 o;
        o.x = f2bf(v.x); o.y = f2bf(v.y); o.z = f2bf(v.z); o.w = f2bf(v.w);
        *reinterpret_cast<ushort4*>(dst + i) = o;
    }
}

// ---------------------------------------------------------------------------
// Weight transpose + convert: Wt[n][k] = bf16(W[k][n]) for all weights.
// ---------------------------------------------------------------------------
__global__ __launch_bounds__(256)
void k_cvt_w(const float* __restrict__ wv, const float* __restrict__ wo,
             const float* __restrict__ wa, const float* __restrict__ wout,
             const float* __restrict__ w1, const float* __restrict__ w2,
             unsigned short* __restrict__ wcat, unsigned short* __restrict__ woutt,
             unsigned short* __restrict__ w1t, unsigned short* __restrict__ w2t)
{
    const int total = 163840 + 65536 + 262144 + 262144;
    for (int gid = blockIdx.x * 256 + threadIdx.x; gid < total; gid += gridDim.x * 256) {
        int local = gid;
        float f; unsigned short* dst;
        if (local < 163840) {                       // wcat_t [640][256]
            int n = local >> 8, k = local & 255;
            if (n < 256)      f = wv[k * 256 + n];
            else if (n < 512) f = wo[k * 256 + (n - 256)];
            else              f = wa[k * 128 + (n - 512)];
            dst = wcat + local;
        } else if ((local -= 163840) < 65536) {     // wout_t [256][256]
            int n = local >> 8, k = local & 255;
            f = wout[k * 256 + n];
            dst = woutt + local;
        } else if ((local -= 65536) < 262144) {     // w1_t [1024][256]
            int n = local >> 8, k = local & 255;
            f = w1[k * 1024 + n];
            dst = w1t + local;
        } else {                                    // w2_t [256][1024]
            local -= 262144;
            int n = local >> 10, k = local & 1023;
            f = w2[k * 256 + n];
            dst = w2t + local;
        }
        *dst = f2bf(f);
    }
}

// ===========================================================================
// GEMM geometry: BM=64, BN=256 (or 128), BK=64, 512 threads = 8 waves (2Mx4N).
// A tile (64x256) RESIDENT in LDS (staged once via global_load_lds,
// 16B-slot XOR-swizzled both sides); W slabs staged per kc into w_s.
// ===========================================================================

// resident A: 64 rows x 256 k, 32KB. chunk g = it*512 + wid*64 + lane.
#define STAGE_A_RES(Aptr, ASTR)                                                \
    _Pragma("unroll")                                                          \
    for (int it = 0; it < 4; ++it) {                                           \
        int g = it * 512 + wid * 64 + lane;                                    \
        int row = g >> 5, c = g & 31;                                          \
        int s = c ^ (row & 7);                                                 \
        gl_lds16(Aptr + (size_t)(m0 + row) * ASTR + s * 8,                     \
                 a_s + (size_t)(it * 512 + wid * 64) * 8);                     \
    }

// W slab: NRND*64 rows x 64 k into w_s (linear, swizzled source)
#define STAGE_W_SLAB(Wptr, WSTR, NRND, kcexp)                                  \
    _Pragma("unroll")                                                          \
    for (int rnd = 0; rnd < NRND; ++rnd) {                                     \
        int row = (rnd << 6) + (wid << 3) + (lane >> 3);                       \
        int slot = (lane & 7) ^ (row & 7);                                     \
        gl_lds16(Wptr + (size_t)(n0 + row) * WSTR + (kcexp) * 64 + slot * 8,   \
                 w_s + (size_t)((rnd << 6) + (wid << 3)) * 64);                \
    }

// A frags (resident a_s) + W frags (w_s) + MFMA, 4 j-columns
#define KSTEP_4J(kcv)                                                          \
    {                                                                          \
        const int ksb = (lane >> 4);                                           \
        bf16x8 af[2][2], bfr[4][2];                                            \
        _Pragma("unroll")                                                      \
        for (int i = 0; i < 2; ++i) {                                          \
            int m = wm * 32 + i * 16 + cl;                                     \
            _Pragma("unroll")                                                  \
            for (int kk = 0; kk < 2; ++kk) {                                   \
                int phys = (kcv) * 8 + (((kk << 2) + ksb) ^ (m & 7));          \
                af[i][kk] = *reinterpret_cast<const bf16x8*>(                  \
                    a_s + m * 256 + phys * 8);                                 \
            }                                                                  \
        }                                                                      \
        _Pragma("unroll")                                                      \
        for (int j = 0; j < 4; ++j) {                                          \
            int n = wn * 64 + j * 16 + cl;                                     \
            _Pragma("unroll")                                                  \
            for (int kk = 0; kk < 2; ++kk) {                                   \
                int phys = ((kk << 2) + ksb) ^ (n & 7);                        \
                bfr[j][kk] = *reinterpret_cast<const bf16x8*>(                 \
                    w_s + n * 64 + phys * 8);                                  \
            }                                                                  \
        }                                                                      \
        _Pragma("unroll")                                                      \
        for (int kk = 0; kk < 2; ++kk)                                         \
            _Pragma("unroll")                                                  \
            for (int i = 0; i < 2; ++i)                                        \
                _Pragma("unroll")                                              \
                for (int j = 0; j < 4; ++j)                                    \
                    acc[i][j] = __builtin_amdgcn_mfma_f32_16x16x32_bf16(       \
                        af[i][kk], bfr[j][kk], acc[i][j], 0, 0, 0);            \
    }

// ---------------------------------------------------------------------------
// Merged projection: per block (64 rows), slabs [value(256) | off(256) |
// att(128, fused softmax)]. A resident; W staged per slab/kc.
// ---------------------------------------------------------------------------
__global__ __launch_bounds__(512)
void k_proj(const unsigned short* __restrict__ A, const unsigned short* __restrict__ Wt,
            const float* __restrict__ b_val, const float* __restrict__ b_off,
            const float* __restrict__ b_att,
            unsigned short* __restrict__ value, unsigned short* __restrict__ offr,
            unsigned short* __restrict__ attw, int M, int nk)
{
    __shared__ __align__(16) unsigned short a_s[64 * 256];   // 32 KB
    __shared__ __align__(16) unsigned short w_s[256 * 64];   // 32 KB (also repack)
    const int tid = threadIdx.x;
    const int m0 = blockIdx.x * 64;
    const int lane = tid & 63, wid = tid >> 6;
    const int wm = wid >> 2, wn = wid & 3;
    const int cl = lane & 15, r4 = (lane >> 4) * 4;

    STAGE_A_RES(A, 256)

    // ---- slabs 0,1: value / off ----
    for (int sl = 0; sl < 2; ++sl) {
        const int n0 = sl * 256;
        f32x4 acc[2][4] = {};
        for (int kc = 0; kc < 4; ++kc) {
            __syncthreads();
            STAGE_W_SLAB(Wt, 256, 4, kc)
            __syncthreads();
            KSTEP_4J(kc)
        }
        const float* bias = (sl == 0) ? b_val : b_off;
        #pragma unroll
        for (int hh = 0; hh < 2; ++hh) {
            __syncthreads();
            if (wm == hh) {
                #pragma unroll
                for (int j = 0; j < 4; ++j) {
                    int col = wn * 64 + j * 16 + cl;
                    float bv = bias[col];
                    #pragma unroll
                    for (int i = 0; i < 2; ++i)
                        #pragma unroll
                        for (int r = 0; r < 4; ++r)
                            w_s[(i * 16 + r4 + r) * 264 + col] =
                                f2bf(acc[i][j][r] + bv);
                }
            }
            __syncthreads();
            #pragma unroll
            for (int t = 0; t < 2; ++t) {
                int idx = tid + t * 512;        // 0..1023 = 32 rows x 32 chunks
                int row = idx >> 5, cu = idx & 31;
                int grow = m0 + hh * 32 + row;
                if (grow < M) {
                    uint4 vv = *reinterpret_cast<const uint4*>(w_s + row * 264 + cu * 8);
                    if (sl == 0) {
                        int b = grow >= nk;
                        int pix = grow - (b ? nk : 0);
                        int hd = cu >> 2, ch = (cu & 3) * 8;
                        *reinterpret_cast<uint4*>(
                            value + ((size_t)(b * 8 + hd) * nk + pix) * 32 + ch) = vv;
                    } else {
                        *reinterpret_cast<uint4*>(offr + (size_t)grow * 256 + cu * 8) = vv;
                    }
                }
            }
        }
    }

    // ---- slab 2: att (128 cols, all 8 waves, 2 j-columns each) ----
    {
        const int n0 = 512;
        f32x4 acc[2][2] = {};
        for (int kc = 0; kc < 4; ++kc) {
            __syncthreads();
            STAGE_W_SLAB(Wt, 256, 2, kc)
            __syncthreads();
            {
                const int ksb = (lane >> 4);
                bf16x8 af[2][2], bfr[2][2];
                #pragma unroll
                for (int i = 0; i < 2; ++i) {
                    int m = wm * 32 + i * 16 + cl;
                    #pragma unroll
                    for (int kk = 0; kk < 2; ++kk) {
                        int phys = kc * 8 + (((kk << 2) + ksb) ^ (m & 7));
                        af[i][kk] = *reinterpret_cast<const bf16x8*>(
                            a_s + m * 256 + phys * 8);
                    }
                }
                #pragma unroll
                for (int j = 0; j < 2; ++j) {
                    int n = wn * 32 + j * 16 + cl;
                    #pragma unroll
                    for (int kk = 0; kk < 2; ++kk) {
                        int phys = ((kk << 2) + ksb) ^ (n & 7);
                        bfr[j][kk] = *reinterpret_cast<const bf16x8*>(
                            w_s + n * 64 + phys * 8);
                    }
                }
                #pragma unroll
                for (int kk = 0; kk < 2; ++kk)
                    #pragma unroll
                    for (int i = 0; i < 2; ++i)
                        #pragma unroll
                        for (int j = 0; j < 2; ++j)
                            acc[i][j] = __builtin_amdgcn_mfma_f32_16x16x32_bf16(
                                af[i][kk], bfr[j][kk], acc[i][j], 0, 0, 0);
            }
        }
        // softmax over 16-col head groups (head = wn*2+j; lanes cl 0..15)
        #pragma unroll
        for (int j = 0; j < 2; ++j) {
            int a = wn * 32 + j * 16 + cl;
            float bv = b_att[a];
            #pragma unroll
            for (int i = 0; i < 2; ++i) {
                #pragma unroll
                for (int r = 0; r < 4; ++r) {
                    float v = acc[i][j][r] + bv;
                    float mx = v;
                    mx = fmaxf(mx, __shfl_xor(mx, 1));
                    mx = fmaxf(mx, __shfl_xor(mx, 2));
                    mx = fmaxf(mx, __shfl_xor(mx, 4));
                    mx = fmaxf(mx, __shfl_xor(mx, 8));
                    float e = __expf(v - mx);
                    float s = e;
                    s += __shfl_xor(s, 1);
                    s += __shfl_xor(s, 2);
                    s += __shfl_xor(s, 4);
                    s += __shfl_xor(s, 8);
                    acc[i][j][r] = e / s;
                }
            }
        }
        __syncthreads();
        #pragma unroll
        for (int j = 0; j < 2; ++j) {
            int a = wn * 32 + j * 16 + cl;
            #pragma unroll
            for (int i = 0; i < 2; ++i)
                #pragma unroll
                for (int r = 0; r < 4; ++r)
                    w_s[(wm * 32 + i * 16 + r4 + r) * 136 + a] = f2bf(acc[i][j][r]);
        }
        __syncthreads();
        #pragma unroll
        for (int t = 0; t < 2; ++t) {
            int idx = tid + t * 512;           // 64 rows x 16 chunks
            int row = idx >> 4, cu = idx & 15;
            int grow = m0 + row;
            if (grow < M)
                *reinterpret_cast<uint4*>(attw + (size_t)grow * 128 + cu * 8) =
                    *reinterpret_cast<const uint4*>(w_s + row * 136 + cu * 8);
        }
    }
}

// ---------------------------------------------------------------------------
// Deformable sampling, HEAD-PARTITIONED blocks for XCD L2 locality (r13).
// ---------------------------------------------------------------------------
__global__ __launch_bounds__(256)
void k_sample(const unsigned short* __restrict__ value,
              const unsigned short* __restrict__ offr,
              const unsigned short* __restrict__ attw,
              const float* __restrict__ ref,
              const int* __restrict__ shapes, const int* __restrict__ lsi,
              unsigned short* __restrict__ core, int M)
{
    __shared__ int2 iw_s[64][65];            // [corner q][token] (pad 65)
    const int tid = threadIdx.x;
    const int bh = blockIdx.x & 15;
    const int grp = blockIdx.x >> 4;
    const int b = bh >> 3, h = bh & 7;
    const int nk = lsi[3] + shapes[6] * shapes[7];
    const int tok0 = grp * 64;

    #pragma unroll
    for (int rnd = 0; rnd < 4; ++rnd) {
        const int lp = tid & 15;             // l*4+p
        const int tk = rnd * 16 + (tid >> 4);
        const int l = lp >> 2;
        const int pix0 = tok0 + tk;
        int2 out[4];
        if (pix0 < nk) {
            const int token = b * nk + pix0;
            const int Hl = shapes[l * 2], Wl = shapes[l * 2 + 1];
            const int pbase = bh * nk + lsi[l];
            const float rx = ref[(size_t)token * 8 + l * 2];
            const float ry = ref[(size_t)token * 8 + l * 2 + 1];
            const unsigned int oxy = *reinterpret_cast<const unsigned int*>(
                offr + (size_t)token * 256 + (h * 16 + lp) * 2);
            const float ox = bf2f((unsigned short)(oxy & 0xffffu));
            const float oy = bf2f((unsigned short)(oxy >> 16));
            const float aw = bf2f(attw[(size_t)token * 128 + h * 16 + lp]);
            const float x = fmaf(rx, (float)Wl, ox) - 0.5f;
            const float y = fmaf(ry, (float)Hl, oy) - 0.5f;
            const float x0f = floorf(x), y0f = floorf(y);
            const float fx = x - x0f, fy = y - y0f;
            const int x0 = (int)x0f, y0 = (int)y0f;
            #pragma unroll
            for (int t = 0; t < 4; ++t) {
                const int dx = t & 1, dy = t >> 1;
                const int xi = x0 + dx, yi = y0 + dy;
                const bool valid = (xi >= 0) & (xi < Wl) & (yi >= 0) & (yi < Hl);
                const float w = (dx ? fx : 1.f - fx) * (dy ? fy : 1.f - fy) * aw;
                const int xc = min(max(xi, 0), Wl - 1);
                const int yc = min(max(yi, 0), Hl - 1);
                out[t].x = (pbase + yc * Wl + xc) * 16;   // u32 chunk offset
                out[t].y = __float_as_int(valid ? w : 0.f);
            }
        } else {
            #pragma unroll
            for (int t = 0; t < 4; ++t) out[t] = make_int2(0, 0);
        }
        #pragma unroll
        for (int t = 0; t < 4; ++t)
            iw_s[lp * 4 + t][tk] = out[t];
    }
    __syncthreads();

    const int tk = tid >> 2;
    const int dp = tid & 3;                  // channel oct: ch 8dp..8dp+7
    const int pix = tok0 + tk;
    const unsigned int* vu = reinterpret_cast<const unsigned int*>(value) + dp * 4;
    f32x2 a0 = {0.f, 0.f}, a1 = {0.f, 0.f};
    f32x2 a2 = {0.f, 0.f}, a3 = {0.f, 0.f};
    #pragma unroll 16
    for (int q = 0; q < 64; ++q) {
        const int2 iw = iw_s[q][tk];
        const float w = __int_as_float(iw.y);
        const f32x2 w2 = {w, w};
        const uint4 v = *reinterpret_cast<const uint4*>(vu + (size_t)(unsigned)iw.x);
        const f32x2 v0 = {__uint_as_float(v.x << 16), __uint_as_float(v.x & 0xffff0000u)};
        const f32x2 v1 = {__uint_as_float(v.y << 16), __uint_as_float(v.y & 0xffff0000u)};
        const f32x2 v2 = {__uint_as_float(v.z << 16), __uint_as_float(v.z & 0xffff0000u)};
        const f32x2 v3 = {__uint_as_float(v.w << 16), __uint_as_float(v.w & 0xffff0000u)};
        a0 = pkfma(v0, w2, a0);
        a1 = pkfma(v1, w2, a1);
        a2 = pkfma(v2, w2, a2);
        a3 = pkfma(v3, w2, a3);
    }
    if (pix < nk) {
        uint4 o;
        o.x = (unsigned int)f2bf(a0.x) | ((unsigned int)f2bf(a0.y) << 16);
        o.y = (unsigned int)f2bf(a1.x) | ((unsigned int)f2bf(a1.y) << 16);
        o.z = (unsigned int)f2bf(a2.x) | ((unsigned int)f2bf(a2.y) << 16);
        o.w = (unsigned int)f2bf(a3.x) | ((unsigned int)f2bf(a3.y) << 16);
        *reinterpret_cast<uint4*>(
            core + (size_t)(b * nk + pix) * 256 + h * 32 + dp * 8) = o;
    }
}

// ---------------------------------------------------------------------------
// Out-projection + residual + LN1 (resident A): x_bf = LN(src + core@wout + b)
// ---------------------------------------------------------------------------
__global__ __launch_bounds__(512)
void k_oproj(const unsigned short* __restrict__ A, const unsigned short* __restrict__ Wt,
             const float* __restrict__ b_out, const float* __restrict__ src,
             const float* __restrict__ g1, const float* __restrict__ bt1,
             unsigned short* __restrict__ X, int M)
{
    __shared__ __align__(16) unsigned short a_s[64 * 256];
    __shared__ __align__(16) unsigned short w_s[256 * 64];
    __shared__ float red[64 * 8];
    __shared__ float mr[64 * 2];
    const int tid = threadIdx.x;
    const int m0 = blockIdx.x * 64;
    const int n0 = 0;
    const int lane = tid & 63, wid = tid >> 6;
    const int wm = wid >> 2, wn = wid & 3;
    const int cl = lane & 15, r4 = (lane >> 4) * 4;

    STAGE_A_RES(A, 256)

    f32x4 acc[2][4] = {};
    for (int kc = 0; kc < 4; ++kc) {
        __syncthreads();
        STAGE_W_SLAB(Wt, 256, 4, kc)
        __syncthreads();
        KSTEP_4J(kc)
    }

    #pragma unroll
    for (int j = 0; j < 4; ++j) {
        int col = wn * 64 + j * 16 + cl;
        float bv = b_out[col];
        #pragma unroll
        for (int i = 0; i < 2; ++i) {
            int mb = wm * 32 + i * 16 + r4;
            #pragma unroll
            for (int r = 0; r < 4; ++r) {
                int row = m0 + mb + r;
                float sv = (row < M) ? src[(size_t)row * 256 + col] : 0.f;
                acc[i][j][r] += bv + sv;
            }
        }
    }
    #pragma unroll
    for (int i = 0; i < 2; ++i)
        #pragma unroll
        for (int r = 0; r < 4; ++r) {
            float s1 = 0.f, s2 = 0.f;
            #pragma unroll
            for (int j = 0; j < 4; ++j) { float t = acc[i][j][r]; s1 += t; s2 += t * t; }
            s1 += __shfl_xor(s1, 1); s2 += __shfl_xor(s2, 1);
            s1 += __shfl_xor(s1, 2); s2 += __shfl_xor(s2, 2);
            s1 += __shfl_xor(s1, 4); s2 += __shfl_xor(s2, 4);
            s1 += __shfl_xor(s1, 8); s2 += __shfl_xor(s2, 8);
            if (cl == 0) {
                int rr = wm * 32 + i * 16 + r4 + r;
                red[(rr * 4 + wn) * 2 + 0] = s1;
                red[(rr * 4 + wn) * 2 + 1] = s2;
            }
        }
    __syncthreads();
    if (tid < 64) {
        float s1 = red[tid * 8] + red[tid * 8 + 2] + red[tid * 8 + 4] + red[tid * 8 + 6];
        float s2 = red[tid * 8 + 1] + red[tid * 8 + 3] + red[tid * 8 + 5] + red[tid * 8 + 7];
        float mu = s1 * (1.f / 256.f);
        mr[tid * 2] = mu;
        mr[tid * 2 + 1] = rsqrtf(fmaxf(s2 * (1.f / 256.f) - mu * mu, 0.f) + 1e-5f);
    }
    __syncthreads();
    #pragma unroll
    for (int hh = 0; hh < 2; ++hh) {
        __syncthreads();
        if (wm == hh) {
            #pragma unroll
            for (int j = 0; j < 4; ++j) {
                int col = wn * 64 + j * 16 + cl;
                float gv = g1[col], bt = bt1[col];
                #pragma unroll
                for (int i = 0; i < 2; ++i)
                    #pragma unroll
                    for (int r = 0; r < 4; ++r) {
                        int lr = i * 16 + r4 + r;
                        int rr = hh * 32 + lr;
                        w_s[lr * 264 + col] =
                            f2bf((acc[i][j][r] - mr[rr * 2]) * mr[rr * 2 + 1] * gv + bt);
                    }
            }
        }
        __syncthreads();
        #pragma unroll
        for (int t = 0; t < 2; ++t) {
            int idx = tid + t * 512;
            int row = idx >> 5, cu = idx & 31;
            int grow = m0 + hh * 32 + row;
            if (grow < M)
                *reinterpret_cast<uint4*>(X + (size_t)grow * 256 + cu * 8) =
                    *reinterpret_cast<const uint4*>(w_s + row * 264 + cu * 8);
        }
    }
}

// ---------------------------------------------------------------------------
// Merged FFN GEMM1: h(M,1024) = relu(x_bf @ W1t^T + b1). A resident, 4 slabs.
// ---------------------------------------------------------------------------
__global__ __launch_bounds__(512)
void k_ffn1(const unsigned short* __restrict__ A, const unsigned short* __restrict__ W1t,
            const float* __restrict__ B1, unsigned short* __restrict__ h, int M)
{
    __shared__ __align__(16) unsigned short a_s[64 * 256];
    __shared__ __align__(16) unsigned short w_s[256 * 64];
    const int tid = threadIdx.x;
    const int m0 = blockIdx.x * 64;
    const int lane = tid & 63, wid = tid >> 6;
    const int wm = wid >> 2, wn = wid & 3;
    const int cl = lane & 15, r4 = (lane >> 4) * 4;

    STAGE_A_RES(A, 256)

    for (int sl = 0; sl < 4; ++sl) {
        const int n0 = sl * 256;
        f32x4 acc[2][4] = {};
        for (int kc = 0; kc < 4; ++kc) {
            __syncthreads();
            STAGE_W_SLAB(W1t, 256, 4, kc)
            __syncthreads();
            KSTEP_4J(kc)
        }
        #pragma unroll
        for (int hh = 0; hh < 2; ++hh) {
            __syncthreads();
            if (wm == hh) {
                #pragma unroll
                for (int j = 0; j < 4; ++j) {
                    int col = wn * 64 + j * 16 + cl;
                    float bv = B1[n0 + col];
                    #pragma unroll
                    for (int i = 0; i < 2; ++i)
                        #pragma unroll
                        for (int r = 0; r < 4; ++r)
                            w_s[(i * 16 + r4 + r) * 264 + col] =
                                f2bf(fmaxf(acc[i][j][r] + bv, 0.f));
                }
            }
            __syncthreads();
            #pragma unroll
            for (int t = 0; t < 2; ++t) {
                int idx = tid + t * 512;
                int row = idx >> 5, cu = idx & 31;
                int grow = m0 + hh * 32 + row;
                if (grow < M)
                    *reinterpret_cast<uint4*>(h + (size_t)grow * 1024 + n0 + cu * 8) =
                        *reinterpret_cast<const uint4*>(w_s + row * 264 + cu * 8);
            }
        }
    }
}

// ---------------------------------------------------------------------------
// FFN GEMM2 + residual + LN2 (r13 form, K=1024): per-kc A+W staging.
// ---------------------------------------------------------------------------
#define GEMM_STAGE2(Aptr, ASTR, Wptr, WSTR, kcexp)                             \
    {                                                                          \
        int row = (wid << 3) + (lane >> 3);                                    \
        int slot = (lane & 7) ^ (row & 7);                                     \
        gl_lds16(Aptr + (size_t)(m0 + row) * ASTR + (kcexp) * 64 + slot * 8,   \
                 a2_s + (size_t)(wid << 3) * 64);                              \
    }                                                                          \
    _Pragma("unroll")                                                          \
    for (int rnd = 0; rnd < 4; ++rnd) {                                        \
        int row = (rnd << 6) + (wid << 3) + (lane >> 3);                       \
        int slot = (lane & 7) ^ (row & 7);                                     \
        gl_lds16(Wptr + (size_t)row * WSTR + (kcexp) * 64 + slot * 8,          \
                 w2_s + (size_t)((rnd << 6) + (wid << 3)) * 64);               \
    }

__global__ __launch_bounds__(512)
void k_ffn2(const unsigned short* __restrict__ h, const unsigned short* __restrict__ W2t,
            const float* __restrict__ B2, const unsigned short* __restrict__ Xbf,
            const float* __restrict__ G2, const float* __restrict__ BT2,
            float* __restrict__ OUT, int M)
{
    __shared__ __align__(16) unsigned short smem[20480];
    unsigned short* a2_s = smem;
    unsigned short* w2_s = smem + 4096;
    __shared__ float red[64 * 8];
    __shared__ float mr[64 * 2];
    const int tid = threadIdx.x;
    const int m0 = blockIdx.x * 64;
    const int lane = tid & 63, wid = tid >> 6;
    const int wm = wid >> 2, wn = wid & 3;
    const int cl = lane & 15, r4 = (lane >> 4) * 4;

    f32x4 acc[2][4] = {};

    for (int kc = 0; kc < 16; ++kc) {
        __syncthreads();
        GEMM_STAGE2(h, 1024, W2t, 1024, kc)
        __syncthreads();
        {
            const int ksb = (lane >> 4);
            bf16x8 af[2][2], bfr[4][2];
            #pragma unroll
            for (int i = 0; i < 2; ++i) {
                int m = wm * 32 + i * 16 + cl;
                #pragma unroll
                for (int kk = 0; kk < 2; ++kk) {
                    int phys = ((kk << 2) + ksb) ^ (m & 7);
                    af[i][kk] = *reinterpret_cast<const bf16x8*>(
                        a2_s + m * 64 + phys * 8);
                }
            }
            #pragma unroll
            for (int j = 0; j < 4; ++j) {
                int n = wn * 64 + j * 16 + cl;
                #pragma unroll
                for (int kk = 0; kk < 2; ++kk) {
                    int phys = ((kk << 2) + ksb) ^ (n & 7);
                    bfr[j][kk] = *reinterpret_cast<const bf16x8*>(
                        w2_s + n * 64 + phys * 8);
                }
            }
            #pragma unroll
            for (int kk = 0; kk < 2; ++kk)
                #pragma unroll
                for (int i = 0; i < 2; ++i)
                    #pragma unroll
                    for (int j = 0; j < 4; ++j)
                        acc[i][j] = __builtin_amdgcn_mfma_f32_16x16x32_bf16(
                            af[i][kk], bfr[j][kk], acc[i][j], 0, 0, 0);
        }
    }

    #pragma unroll
    for (int j = 0; j < 4; ++j) {
        int col = wn * 64 + j * 16 + cl;
        float bv = B2[col];
        #pragma unroll
        for (int i = 0; i < 2; ++i) {
            int mb = wm * 32 + i * 16 + r4;
            #pragma unroll
            for (int r = 0; r < 4; ++r) {
                int row = m0 + mb + r;
                float xv = (row < M) ? bf2f(Xbf[(size_t)row * 256 + col]) : 0.f;
                acc[i][j][r] += bv + xv;
            }
        }
    }
    #pragma unroll
    for (int i = 0; i < 2; ++i)
        #pragma unroll
        for (int r = 0; r < 4; ++r) {
            float s1 = 0.f, s2 = 0.f;
            #pragma unroll
            for (int j = 0; j < 4; ++j) { float t = acc[i][j][r]; s1 += t; s2 += t * t; }
            s1 += __shfl_xor(s1, 1); s2 += __shfl_xor(s2, 1);
            s1 += __shfl_xor(s1, 2); s2 += __shfl_xor(s2, 2);
            s1 += __shfl_xor(s1, 4); s2 += __shfl_xor(s2, 4);
            s1 += __shfl_xor(s1, 8); s2 += __shfl_xor(s2, 8);
            if (cl == 0) {
                int rr = wm * 32 + i * 16 + r4 + r;
                red[(rr * 4 + wn) * 2 + 0] = s1;
                red[(rr * 4 + wn) * 2 + 1] = s2;
            }
        }
    __syncthreads();
    if (tid < 64) {
        float s1 = red[tid * 8] + red[tid * 8 + 2] + red[tid * 8 + 4] + red[tid * 8 + 6];
        float s2 = red[tid * 8 + 1] + red[tid * 8 + 3] + red[tid * 8 + 5] + red[tid * 8 + 7];
        float mu = s1 * (1.f / 256.f);
        mr[tid * 2] = mu;
        mr[tid * 2 + 1] = rsqrtf(fmaxf(s2 * (1.f / 256.f) - mu * mu, 0.f) + 1e-5f);
    }
    __syncthreads();
    #pragma unroll
    for (int j = 0; j < 4; ++j) {
        int col = wn * 64 + j * 16 + cl;
        float gv = G2[col], bt = BT2[col];
        #pragma unroll
        for (int i = 0; i < 2; ++i) {
            int mb = wm * 32 + i * 16 + r4;
            #pragma unroll
            for (int r = 0; r < 4; ++r) {
                int rr = mb + r, row = m0 + rr;
                if (row < M)
                    OUT[(size_t)row * 256 + col] =
                        (acc[i][j][r] - mr[rr * 2]) * mr[rr * 2 + 1] * gv + bt;
            }
        }
    }
}

// ---------------------------------------------------------------------------
extern "C" void kernel_launch(void* const* d_in, const int* in_sizes, int n_in,
                              void* d_out, int out_size, void* d_ws, size_t ws_size,
                              hipStream_t stream) {
    const float* src    = (const float*)d_in[0];
    const float* ref    = (const float*)d_in[1];
    const int*   shapes = (const int*)d_in[2];
    const int*   lsi    = (const int*)d_in[3];
    const float* b_off  = (const float*)d_in[5];
    const float* b_att  = (const float*)d_in[7];
    const float* b_val  = (const float*)d_in[9];
    const float* b_out  = (const float*)d_in[11];
    const float* g1     = (const float*)d_in[12];
    const float* bt1    = (const float*)d_in[13];
    const float* b1     = (const float*)d_in[15];
    const float* b2     = (const float*)d_in[17];
    const float* g2     = (const float*)d_in[18];
    const float* bt2    = (const float*)d_in[19];
    const float* w_off  = (const float*)d_in[4];
    const float* w_att  = (const float*)d_in[6];
    const float* w_val  = (const float*)d_in[8];
    const float* w_out  = (const float*)d_in[10];
    const float* w1     = (const float*)d_in[14];
    const float* w2     = (const float*)d_in[16];

    const int M = in_sizes[0] / EMBED;  // B*nq = 49130
    const int nk = M / 2;               // B == 2
    const size_t M256 = (size_t)M * 256;

    unsigned short* w16     = (unsigned short*)d_ws;
    unsigned short* src_bf  = w16;
    unsigned short* value_bf = src_bf + M256;
    unsigned short* offr_bf = value_bf + M256;
    unsigned short* core_bf = offr_bf + M256;
    unsigned short* x_bf    = core_bf + M256;
    unsigned short* attw_bf = x_bf + M256;               // M*128
    unsigned short* wcat    = attw_bf + (size_t)M * 128; // 640*256
    unsigned short* woutt   = wcat + 163840;             // 256*256
    unsigned short* w1t     = woutt + 65536;             // 1024*256
    unsigned short* w2t     = w1t + 262144;              // 256*1024
    // h aliases [src_bf, value, offr, core] (all dead before k_ffn1): M*1024
    unsigned short* h_bf    = w16;

    const int gb64 = (M + 63) / 64;
    const int ngrp = (nk + 63) / 64;

    k_cvt_src<<<4096, 256, 0, stream>>>(src, src_bf, M * 256);
    k_cvt_w<<<2944, 256, 0, stream>>>(w_val, w_off, w_att, w_out, w1, w2,
                                      wcat, woutt, w1t, w2t);
    k_proj<<<gb64, 512, 0, stream>>>(src_bf, wcat, b_val, b_off, b_att,
                                     value_bf, offr_bf, attw_bf, M, nk);
    k_sample<<<ngrp * 16, 256, 0, stream>>>(value_bf, offr_bf, attw_bf, ref,
                                            shapes, lsi, core_bf, M);
    k_oproj<<<gb64, 512, 0, stream>>>(core_bf, woutt, b_out, src, g1, bt1, x_bf, M);
    k_ffn1<<<gb64, 512, 0, stream>>>(x_bf, w1t, b1, h_bf, M);
    k_ffn2<<<gb64, 512, 0, stream>>>(h_bf, w2t, b2, x_bf, g2, bt2,
                                     (float*)d_out, M);
}

// Round 15
// 256.669 us; speedup vs baseline: 1.0897x; 1.0897x over previous
//
#include <hip/hip_runtime.h>
#include <math.h>

#define EMBED 256
#define HEADS 8
#define LEVELS 4
#define POINTS 4
#define FFNDIM 1024

typedef float f32x4 __attribute__((ext_vector_type(4)));
typedef float f32x2 __attribute__((ext_vector_type(2)));
typedef __bf16 bf16x8 __attribute__((ext_vector_type(8)));

static __device__ __forceinline__ float4 ld4f(const float* p) {
    return *reinterpret_cast<const float4*>(p);
}
static __device__ __forceinline__ unsigned short f2bf(float f) {
    unsigned int u = __float_as_uint(f);
    unsigned int r = (u + 0x7fffu + ((u >> 16) & 1u)) >> 16;
    return (unsigned short)r;
}
static __device__ __forceinline__ float bf2f(unsigned short u) {
    return __uint_as_float((unsigned int)u << 16);
}
static __device__ __forceinline__ f32x2 pkfma(f32x2 a, f32x2 b, f32x2 c) {
#if __has_builtin(__builtin_elementwise_fma)
    return __builtin_elementwise_fma(a, b, c);
#else
    f32x2 r; r.x = fmaf(a.x, b.x, c.x); r.y = fmaf(a.y, b.y, c.y); return r;
#endif
}
// async global->LDS, 16B per lane. LDS dest = wave-uniform base + lane*16.
static __device__ __forceinline__
void gl_lds16(const unsigned short* g, unsigned short* l) {
    __builtin_amdgcn_global_load_lds(
        (const __attribute__((address_space(1))) unsigned int*)g,
        (__attribute__((address_space(3))) unsigned int*)l, 16, 0, 0);
}

// ---------------------------------------------------------------------------
// Combined conversion: src fp32->bf16 (vectorized) + weight transpose/convert.
// Work items: [0, n4) = float4 chunks of src; [n4, n4+753664) = weight elems.
// ---------------------------------------------------------------------------
__global__ __launch_bounds__(256)
void k_cvt_all(const float* __restrict__ src, unsigned short* __restrict__ dst,
               int n4,
               const float* __restrict__ wv, const float* __restrict__ wo,
               const float* __restrict__ wa, const float* __restrict__ wout,
               const float* __restrict__ w1, const float* __restrict__ w2,
               unsigned short* __restrict__ wcat, unsigned short* __restrict__ woutt,
               unsigned short* __restrict__ w1t, unsigned short* __restrict__ w2t)
{
    const int wtotal = 163840 + 65536 + 262144 + 262144;
    const int total = n4 + wtotal;
    for (int gid = blockIdx.x * 256 + threadIdx.x; gid < total; gid += gridDim.x * 256) {
        if (gid < n4) {
            float4 v = ld4f(src + (size_t)gid * 4);
            ushort4 o;
            o.x = f2bf(v.x); o.y = f2bf(v.y); o.z = f2bf(v.z); o.w = f2bf(v.w);
            *reinterpret_cast<ushort4*>(dst + (size_t)gid * 4) = o;
        } else {
            int local = gid - n4;
            float f; unsigned short* dp;
            if (local < 163840) {                       // wcat_t [640][256]
                int n = local >> 8, k = local & 255;
                if (n < 256)      f = wv[k * 256 + n];
                else if (n < 512) f = wo[k * 256 + (n - 256)];
                else              f = wa[k * 128 + (n - 512)];
                dp = wcat + local;
            } else if ((local -= 163840) < 65536) {     // wout_t [256][256]
                int n = local >> 8, k = local & 255;
                f = wout[k * 256 + n];
                dp = woutt + local;
            } else if ((local -= 65536) < 262144) {     // w1_t [1024][256]
                int n = local >> 8, k = local & 255;
                f = w1[k * 1024 + n];
                dp = w1t + local;
            } else {                                    // w2_t [256][1024]
                local -= 262144;
                int n = local >> 10, k = local & 1023;
                f = w2[k * 256 + n];
                dp = w2t + local;
            }
            *dp = f2bf(f);
        }
    }
}

// ===========================================================================
// Shared GEMM geometry: BM=64, BN=256, BK=64, 512 threads = 8 waves (2Mx4N).
// Staging via global_load_lds width=16 into LINEAR LDS; bank conflicts
// avoided by XOR-swizzling the 16B slot on BOTH global source and ds_read.
// ===========================================================================

#define GEMM_STAGE(Aptr, ASTR, Wptr, WSTR, kcexp)                              \
    {                                                                          \
        int row = (wid << 3) + (lane >> 3);                                    \
        int slot = (lane & 7) ^ (row & 7);                                     \
        gl_lds16(Aptr + (size_t)(m0 + row) * ASTR + (kcexp) * 64 + slot * 8,   \
                 a_s + (size_t)(wid << 3) * 64);                               \
    }                                                                          \
    _Pragma("unroll")                                                          \
    for (int rnd = 0; rnd < 4; ++rnd) {                                        \
        int row = (rnd << 6) + (wid << 3) + (lane >> 3);                       \
        int slot = (lane & 7) ^ (row & 7);                                     \
        gl_lds16(Wptr + (size_t)(n0 + row) * WSTR + (kcexp) * 64 + slot * 8,   \
                 w_s + (size_t)((rnd << 6) + (wid << 3)) * 64);                \
    }

#define GEMM_FRAGS_MFMA                                                        \
    {                                                                          \
        bf16x8 af[2][2], bfr[4][2];                                            \
        const int ksb = (lane >> 4);                                           \
        _Pragma("unroll")                                                      \
        for (int i = 0; i < 2; ++i) {                                          \
            int m = wm * 32 + i * 16 + cl;                                     \
            _Pragma("unroll")                                                  \
            for (int kk = 0; kk < 2; ++kk) {                                   \
                int phys = (kk * 4 + ksb) ^ (m & 7);                           \
                af[i][kk] = *reinterpret_cast<const bf16x8*>(                  \
                    a_s + m * 64 + phys * 8);                                  \
            }                                                                  \
        }                                                                      \
        _Pragma("unroll")                                                      \
        for (int j = 0; j < 4; ++j) {                                          \
            int n = wn * 64 + j * 16 + cl;                                     \
            _Pragma("unroll")                                                  \
            for (int kk = 0; kk < 2; ++kk) {                                   \
                int phys = (kk * 4 + ksb) ^ (n & 7);                           \
                bfr[j][kk] = *reinterpret_cast<const bf16x8*>(                 \
                    w_s + n * 64 + phys * 8);                                  \
            }                                                                  \
        }                                                                      \
        _Pragma("unroll")                                                      \
        for (int kk = 0; kk < 2; ++kk)                                         \
            _Pragma("unroll")                                                  \
            for (int i = 0; i < 2; ++i)                                        \
                _Pragma("unroll")                                              \
                for (int j = 0; j < 4; ++j)                                    \
                    acc[i][j] = __builtin_amdgcn_mfma_f32_16x16x32_bf16(       \
                        af[i][kk], bfr[j][kk], acc[i][j], 0, 0, 0);            \
    }

// ---------------------------------------------------------------------------
// Projection GEMM: [value|off|att](M,640) = src_bf(M,256) @ wcat_t^T + bias
// grid.y: 0=value(HEAD-MAJOR out: [(b*8+h)][nk][32]), 1=off, 2=att(softmax16).
// ---------------------------------------------------------------------------
__global__ __launch_bounds__(512)
void k_proj(const unsigned short* __restrict__ A, const unsigned short* __restrict__ Wt,
            const float* __restrict__ b_val, const float* __restrict__ b_off,
            const float* __restrict__ b_att,
            unsigned short* __restrict__ value, unsigned short* __restrict__ offr,
            unsigned short* __restrict__ attw, int M, int nk)
{
    __shared__ __align__(16) unsigned short smem[20480];  // 40 KB
    unsigned short* a_s = smem;                           // 64 x 64
    unsigned short* w_s = smem + 4096;                    // 256 x 64
    const int tid = threadIdx.x;
    const int m0 = blockIdx.x * 64;
    const int y = blockIdx.y;
    const int n0 = y * 256;
    const int lane = tid & 63, wid = tid >> 6;
    const int wm = wid >> 2, wn = wid & 3;
    const int cl = lane & 15, r4 = (lane >> 4) * 4;

    f32x4 acc[2][4] = {};

    for (int kc = 0; kc < 4; ++kc) {
        __syncthreads();
        GEMM_STAGE(A, 256, Wt, 256, kc)
        __syncthreads();
        GEMM_FRAGS_MFMA
    }

    if (y < 2) {
        const float* bias = (y == 0) ? b_val : b_off;
        __syncthreads();
        #pragma unroll
        for (int j = 0; j < 4; ++j) {
            int col = wn * 64 + j * 16 + cl;
            float bv = bias[col];
            #pragma unroll
            for (int i = 0; i < 2; ++i)
                #pragma unroll
                for (int r = 0; r < 4; ++r)
                    smem[(wm * 32 + i * 16 + r4 + r) * 264 + col] = f2bf(acc[i][j][r] + bv);
        }
        __syncthreads();
        if (y == 0) {
            // head-major value store: 64B chunk per (row, head)
            #pragma unroll
            for (int t = 0; t < 4; ++t) {
                int idx = tid + t * 512;
                int row = idx >> 5, cu = idx & 31;
                int grow = m0 + row;
                if (grow < M) {
                    int b = grow >= nk;
                    int pix = grow - (b ? nk : 0);
                    int hh = cu >> 2, ch = (cu & 3) * 8;
                    *reinterpret_cast<uint4*>(
                        value + ((size_t)(b * 8 + hh) * nk + pix) * 32 + ch) =
                        *reinterpret_cast<const uint4*>(smem + row * 264 + cu * 8);
                }
            }
        } else {
            #pragma unroll
            for (int t = 0; t < 4; ++t) {
                int idx = tid + t * 512;
                int row = idx >> 5, cu = idx & 31;
                int grow = m0 + row;
                if (grow < M)
                    *reinterpret_cast<uint4*>(offr + (size_t)grow * 256 + cu * 8) =
                        *reinterpret_cast<const uint4*>(smem + row * 264 + cu * 8);
            }
        }
    } else {
        if (wn < 2) {
            #pragma unroll
            for (int j = 0; j < 4; ++j) {
                int a = wn * 64 + j * 16 + cl;
                float bv = b_att[a];
                #pragma unroll
                for (int i = 0; i < 2; ++i) {
                    #pragma unroll
                    for (int r = 0; r < 4; ++r) {
                        float v = acc[i][j][r] + bv;
                        float mx = v;
                        mx = fmaxf(mx, __shfl_xor(mx, 1));
                        mx = fmaxf(mx, __shfl_xor(mx, 2));
                        mx = fmaxf(mx, __shfl_xor(mx, 4));
                        mx = fmaxf(mx, __shfl_xor(mx, 8));
                        float e = __expf(v - mx);
                        float s = e;
                        s += __shfl_xor(s, 1);
                        s += __shfl_xor(s, 2);
                        s += __shfl_xor(s, 4);
                        s += __shfl_xor(s, 8);
                        acc[i][j][r] = e / s;
                    }
                }
            }
        }
        __syncthreads();
        if (wn < 2) {
            #pragma unroll
            for (int j = 0; j < 4; ++j) {
                int a = wn * 64 + j * 16 + cl;
                #pragma unroll
                for (int i = 0; i < 2; ++i)
                    #pragma unroll
                    for (int r = 0; r < 4; ++r)
                        smem[(wm * 32 + i * 16 + r4 + r) * 136 + a] = f2bf(acc[i][j][r]);
            }
        }
        __syncthreads();
        #pragma unroll
        for (int t = 0; t < 2; ++t) {
            int idx = tid + t * 512;           // 0..1023
            int row = idx >> 4, cu = idx & 15;
            int grow = m0 + row;
            if (grow < M)
                *reinterpret_cast<uint4*>(attw + (size_t)grow * 128 + cu * 8) =
                    *reinterpret_cast<const uint4*>(smem + row * 136 + cu * 8);
        }
    }
}

// ---------------------------------------------------------------------------
// Deformable sampling, HEAD-PARTITIONED blocks for XCD L2 locality.
// blockIdx.x = grp*16 + bh  (bh = b*8+h). Round-robin dispatch puts all
// blocks of head h on XCD h%8 -> per-XCD working set = 2 x 1.57MB < 4MB L2.
// ---------------------------------------------------------------------------
__global__ __launch_bounds__(256)
void k_sample(const unsigned short* __restrict__ value,
              const unsigned short* __restrict__ offr,
              const unsigned short* __restrict__ attw,
              const float* __restrict__ ref,
              const int* __restrict__ shapes, const int* __restrict__ lsi,
              unsigned short* __restrict__ core, int M)
{
    __shared__ int2 iw_s[64][65];            // [corner q][token] (pad 65)
    const int tid = threadIdx.x;
    const int bh = blockIdx.x & 15;
    const int grp = blockIdx.x >> 4;
    const int b = bh >> 3, h = bh & 7;
    const int nk = lsi[3] + shapes[6] * shapes[7];
    const int tok0 = grp * 64;

    #pragma unroll
    for (int rnd = 0; rnd < 4; ++rnd) {
        const int lp = tid & 15;             // l*4+p
        const int tk = rnd * 16 + (tid >> 4);
        const int l = lp >> 2;
        const int pix0 = tok0 + tk;
        int2 out[4];
        if (pix0 < nk) {
            const int token = b * nk + pix0;
            const int Hl = shapes[l * 2], Wl = shapes[l * 2 + 1];
            const int pbase = bh * nk + lsi[l];
            const float rx = ref[(size_t)token * 8 + l * 2];
            const float ry = ref[(size_t)token * 8 + l * 2 + 1];
            const unsigned int oxy = *reinterpret_cast<const unsigned int*>(
                offr + (size_t)token * 256 + (h * 16 + lp) * 2);
            const float ox = bf2f((unsigned short)(oxy & 0xffffu));
            const float oy = bf2f((unsigned short)(oxy >> 16));
            const float aw = bf2f(attw[(size_t)token * 128 + h * 16 + lp]);
            const float x = fmaf(rx, (float)Wl, ox) - 0.5f;
            const float y = fmaf(ry, (float)Hl, oy) - 0.5f;
            const float x0f = floorf(x), y0f = floorf(y);
            const float fx = x - x0f, fy = y - y0f;
            const int x0 = (int)x0f, y0 = (int)y0f;
            #pragma unroll
            for (int t = 0; t < 4; ++t) {
                const int dx = t & 1, dy = t >> 1;
                const int xi = x0 + dx, yi = y0 + dy;
                const bool valid = (xi >= 0) & (xi < Wl) & (yi >= 0) & (yi < Hl);
                const float w = (dx ? fx : 1.f - fx) * (dy ? fy : 1.f - fy) * aw;
                const int xc = min(max(xi, 0), Wl - 1);
                const int yc = min(max(yi, 0), Hl - 1);
                out[t].x = (pbase + yc * Wl + xc) * 16;   // u32 chunk offset
                out[t].y = __float_as_int(valid ? w : 0.f);
            }
        } else {
            #pragma unroll
            for (int t = 0; t < 4; ++t) out[t] = make_int2(0, 0);
        }
        #pragma unroll
        for (int t = 0; t < 4; ++t)
            iw_s[lp * 4 + t][tk] = out[t];
    }
    __syncthreads();

    const int tk = tid >> 2;
    const int dp = tid & 3;                  // channel oct: ch 8dp..8dp+7
    const int pix = tok0 + tk;
    const unsigned int* vu = reinterpret_cast<const unsigned int*>(value) + dp * 4;
    f32x2 a0 = {0.f, 0.f}, a1 = {0.f, 0.f};
    f32x2 a2 = {0.f, 0.f}, a3 = {0.f, 0.f};
    #pragma unroll 16
    for (int q = 0; q < 64; ++q) {
        const int2 iw = iw_s[q][tk];
        const float w = __int_as_float(iw.y);
        const f32x2 w2 = {w, w};
        const uint4 v = *reinterpret_cast<const uint4*>(vu + (size_t)(unsigned)iw.x);
        const f32x2 v0 = {__uint_as_float(v.x << 16), __uint_as_float(v.x & 0xffff0000u)};
        const f32x2 v1 = {__uint_as_float(v.y << 16), __uint_as_float(v.y & 0xffff0000u)};
        const f32x2 v2 = {__uint_as_float(v.z << 16), __uint_as_float(v.z & 0xffff0000u)};
        const f32x2 v3 = {__uint_as_float(v.w << 16), __uint_as_float(v.w & 0xffff0000u)};
        a0 = pkfma(v0, w2, a0);
        a1 = pkfma(v1, w2, a1);
        a2 = pkfma(v2, w2, a2);
        a3 = pkfma(v3, w2, a3);
    }
    if (pix < nk) {
        uint4 o;
        o.x = (unsigned int)f2bf(a0.x) | ((unsigned int)f2bf(a0.y) << 16);
        o.y = (unsigned int)f2bf(a1.x) | ((unsigned int)f2bf(a1.y) << 16);
        o.z = (unsigned int)f2bf(a2.x) | ((unsigned int)f2bf(a2.y) << 16);
        o.w = (unsigned int)f2bf(a3.x) | ((unsigned int)f2bf(a3.y) << 16);
        *reinterpret_cast<uint4*>(
            core + (size_t)(b * nk + pix) * 256 + h * 32 + dp * 8) = o;
    }
}

// ---------------------------------------------------------------------------
// Out-projection + residual + LN1: x_bf = LN(src + core_bf @ wout + b_out)
// ---------------------------------------------------------------------------
__global__ __launch_bounds__(512)
void k_oproj(const unsigned short* __restrict__ A, const unsigned short* __restrict__ Wt,
             const float* __restrict__ b_out, const float* __restrict__ src,
             const float* __restrict__ g1, const float* __restrict__ bt1,
             unsigned short* __restrict__ X, int M)
{
    __shared__ __align__(16) unsigned short smem[20480];
    unsigned short* a_s = smem;
    unsigned short* w_s = smem + 4096;
    __shared__ float red[64 * 8];
    __shared__ float mr[64 * 2];
    const int tid = threadIdx.x;
    const int m0 = blockIdx.x * 64;
    const int n0 = 0;
    const int lane = tid & 63, wid = tid >> 6;
    const int wm = wid >> 2, wn = wid & 3;
    const int cl = lane & 15, r4 = (lane >> 4) * 4;

    f32x4 acc[2][4] = {};

    for (int kc = 0; kc < 4; ++kc) {
        __syncthreads();
        GEMM_STAGE(A, 256, Wt, 256, kc)
        __syncthreads();
        GEMM_FRAGS_MFMA
    }

    #pragma unroll
    for (int j = 0; j < 4; ++j) {
        int col = wn * 64 + j * 16 + cl;
        float bv = b_out[col];
        #pragma unroll
        for (int i = 0; i < 2; ++i) {
            int mb = wm * 32 + i * 16 + r4;
            #pragma unroll
            for (int r = 0; r < 4; ++r) {
                int row = m0 + mb + r;
                float sv = (row < M) ? src[(size_t)row * 256 + col] : 0.f;
                acc[i][j][r] += bv + sv;
            }
        }
    }
    #pragma unroll
    for (int i = 0; i < 2; ++i)
        #pragma unroll
        for (int r = 0; r < 4; ++r) {
            float s1 = 0.f, s2 = 0.f;
            #pragma unroll
            for (int j = 0; j < 4; ++j) { float t = acc[i][j][r]; s1 += t; s2 += t * t; }
            s1 += __shfl_xor(s1, 1); s2 += __shfl_xor(s2, 1);
            s1 += __shfl_xor(s1, 2); s2 += __shfl_xor(s2, 2);
            s1 += __shfl_xor(s1, 4); s2 += __shfl_xor(s2, 4);
            s1 += __shfl_xor(s1, 8); s2 += __shfl_xor(s2, 8);
            if (cl == 0) {
                int rr = wm * 32 + i * 16 + r4 + r;
                red[(rr * 4 + wn) * 2 + 0] = s1;
                red[(rr * 4 + wn) * 2 + 1] = s2;
            }
        }
    __syncthreads();
    if (tid < 64) {
        float s1 = red[tid * 8] + red[tid * 8 + 2] + red[tid * 8 + 4] + red[tid * 8 + 6];
        float s2 = red[tid * 8 + 1] + red[tid * 8 + 3] + red[tid * 8 + 5] + red[tid * 8 + 7];
        float mu = s1 * (1.f / 256.f);
        mr[tid * 2] = mu;
        mr[tid * 2 + 1] = rsqrtf(fmaxf(s2 * (1.f / 256.f) - mu * mu, 0.f) + 1e-5f);
    }
    __syncthreads();
    #pragma unroll
    for (int j = 0; j < 4; ++j) {
        int col = wn * 64 + j * 16 + cl;
        float gv = g1[col], bt = bt1[col];
        #pragma unroll
        for (int i = 0; i < 2; ++i)
            #pragma unroll
            for (int r = 0; r < 4; ++r) {
                int rr = wm * 32 + i * 16 + r4 + r;
                smem[rr * 264 + col] =
                    f2bf((acc[i][j][r] - mr[rr * 2]) * mr[rr * 2 + 1] * gv + bt);
            }
    }
    __syncthreads();
    #pragma unroll
    for (int t = 0; t < 4; ++t) {
        int idx = tid + t * 512;
        int row = idx >> 5, cu = idx & 31;
        int grow = m0 + row;
        if (grow < M)
            *reinterpret_cast<uint4*>(X + (size_t)grow * 256 + cu * 8) =
                *reinterpret_cast<const uint4*>(smem + row * 264 + cu * 8);
    }
}

// ---------------------------------------------------------------------------
// FFN GEMM1: h(M,1024) = relu(x_bf @ W1t^T + b1). grid.y = 256-col slab.
// ---------------------------------------------------------------------------
__global__ __launch_bounds__(512)
void k_ffn1(const unsigned short* __restrict__ A, const unsigned short* __restrict__ W1t,
            const float* __restrict__ B1, unsigned short* __restrict__ h, int M)
{
    __shared__ __align__(16) unsigned short smem[20480];
    unsigned short* a_s = smem;
    unsigned short* w_s = smem + 4096;
    const int tid = threadIdx.x;
    const int m0 = blockIdx.x * 64;
    const int n0 = blockIdx.y * 256;
    const int lane = tid & 63, wid = tid >> 6;
    const int wm = wid >> 2, wn = wid & 3;
    const int cl = lane & 15, r4 = (lane >> 4) * 4;

    f32x4 acc[2][4] = {};

    for (int kc = 0; kc < 4; ++kc) {
        __syncthreads();
        GEMM_STAGE(A, 256, W1t, 256, kc)
        __syncthreads();
        GEMM_FRAGS_MFMA
    }

    __syncthreads();
    #pragma unroll
    for (int j = 0; j < 4; ++j) {
        int col = wn * 64 + j * 16 + cl;
        float bv = B1[n0 + col];
        #pragma unroll
        for (int i = 0; i < 2; ++i)
            #pragma unroll
            for (int r = 0; r < 4; ++r)
                smem[(wm * 32 + i * 16 + r4 + r) * 264 + col] =
                    f2bf(fmaxf(acc[i][j][r] + bv, 0.f));
    }
    __syncthreads();
    #pragma unroll
    for (int t = 0; t < 4; ++t) {
        int idx = tid + t * 512;
        int row = idx >> 5, cu = idx & 31;
        int grow = m0 + row;
        if (grow < M)
            *reinterpret_cast<uint4*>(h + (size_t)grow * 1024 + n0 + cu * 8) =
                *reinterpret_cast<const uint4*>(smem + row * 264 + cu * 8);
    }
}

// ---------------------------------------------------------------------------
// FFN GEMM2 + residual + LN2: out = LN(x_bf + h @ W2t^T + b2), fp32 out.
// K=1024 (16 kc steps).
// ---------------------------------------------------------------------------
__global__ __launch_bounds__(512)
void k_ffn2(const unsigned short* __restrict__ h, const unsigned short* __restrict__ W2t,
            const float* __restrict__ B2, const unsigned short* __restrict__ Xbf,
            const float* __restrict__ G2, const float* __restrict__ BT2,
            float* __restrict__ OUT, int M)
{
    __shared__ __align__(16) unsigned short smem[20480];
    unsigned short* a_s = smem;
    unsigned short* w_s = smem + 4096;
    __shared__ float red[64 * 8];
    __shared__ float mr[64 * 2];
    const int tid = threadIdx.x;
    const int m0 = blockIdx.x * 64;
    const int n0 = 0;
    const int lane = tid & 63, wid = tid >> 6;
    const int wm = wid >> 2, wn = wid & 3;
    const int cl = lane & 15, r4 = (lane >> 4) * 4;

    f32x4 acc[2][4] = {};

    for (int kc = 0; kc < 16; ++kc) {
        __syncthreads();
        GEMM_STAGE(h, 1024, W2t, 1024, kc)
        __syncthreads();
        GEMM_FRAGS_MFMA
    }

    // epilogue: v = acc + b2 + x (bf16 residual); LN2; fp32 out
    #pragma unroll
    for (int j = 0; j < 4; ++j) {
        int col = wn * 64 + j * 16 + cl;
        float bv = B2[col];
        #pragma unroll
        for (int i = 0; i < 2; ++i) {
            int mb = wm * 32 + i * 16 + r4;
            #pragma unroll
            for (int r = 0; r < 4; ++r) {
                int row = m0 + mb + r;
                float xv = (row < M) ? bf2f(Xbf[(size_t)row * 256 + col]) : 0.f;
                acc[i][j][r] += bv + xv;
            }
        }
    }
    #pragma unroll
    for (int i = 0; i < 2; ++i)
        #pragma unroll
        for (int r = 0; r < 4; ++r) {
            float s1 = 0.f, s2 = 0.f;
            #pragma unroll
            for (int j = 0; j < 4; ++j) { float t = acc[i][j][r]; s1 += t; s2 += t * t; }
            s1 += __shfl_xor(s1, 1); s2 += __shfl_xor(s2, 1);
            s1 += __shfl_xor(s1, 2); s2 += __shfl_xor(s2, 2);
            s1 += __shfl_xor(s1, 4); s2 += __shfl_xor(s2, 4);
            s1 += __shfl_xor(s1, 8); s2 += __shfl_xor(s2, 8);
            if (cl == 0) {
                int rr = wm * 32 + i * 16 + r4 + r;
                red[(rr * 4 + wn) * 2 + 0] = s1;
                red[(rr * 4 + wn) * 2 + 1] = s2;
            }
        }
    __syncthreads();
    if (tid < 64) {
        float s1 = red[tid * 8] + red[tid * 8 + 2] + red[tid * 8 + 4] + red[tid * 8 + 6];
        float s2 = red[tid * 8 + 1] + red[tid * 8 + 3] + red[tid * 8 + 5] + red[tid * 8 + 7];
        float mu = s1 * (1.f / 256.f);
        mr[tid * 2] = mu;
        mr[tid * 2 + 1] = rsqrtf(fmaxf(s2 * (1.f / 256.f) - mu * mu, 0.f) + 1e-5f);
    }
    __syncthreads();
    #pragma unroll
    for (int j = 0; j < 4; ++j) {
        int col = wn * 64 + j * 16 + cl;
        float gv = G2[col], bt = BT2[col];
        #pragma unroll
        for (int i = 0; i < 2; ++i) {
            int mb = wm * 32 + i * 16 + r4;
            #pragma unroll
            for (int r = 0; r < 4; ++r) {
                int rr = mb + r, row = m0 + rr;
                if (row < M)
                    OUT[(size_t)row * 256 + col] =
                        (acc[i][j][r] - mr[rr * 2]) * mr[rr * 2 + 1] * gv + bt;
            }
        }
    }
}

// ---------------------------------------------------------------------------
extern "C" void kernel_launch(void* const* d_in, const int* in_sizes, int n_in,
                              void* d_out, int out_size, void* d_ws, size_t ws_size,
                              hipStream_t stream) {
    const float* src    = (const float*)d_in[0];
    const float* ref    = (const float*)d_in[1];
    const int*   shapes = (const int*)d_in[2];
    const int*   lsi    = (const int*)d_in[3];
    const float* b_off  = (const float*)d_in[5];
    const float* b_att  = (const float*)d_in[7];
    const float* b_val  = (const float*)d_in[9];
    const float* b_out  = (const float*)d_in[11];
    const float* g1     = (const float*)d_in[12];
    const float* bt1    = (const float*)d_in[13];
    const float* b1     = (const float*)d_in[15];
    const float* b2     = (const float*)d_in[17];
    const float* g2     = (const float*)d_in[18];
    const float* bt2    = (const float*)d_in[19];
    const float* w_off  = (const float*)d_in[4];
    const float* w_att  = (const float*)d_in[6];
    const float* w_val  = (const float*)d_in[8];
    const float* w_out  = (const float*)d_in[10];
    const float* w1     = (const float*)d_in[14];
    const float* w2     = (const float*)d_in[16];

    const int M = in_sizes[0] / EMBED;  // B*nq = 49130
    const int nk = M / 2;               // B == 2
    const size_t M256 = (size_t)M * 256;

    unsigned short* w16     = (unsigned short*)d_ws;
    unsigned short* src_bf  = w16;
    unsigned short* value_bf = src_bf + M256;
    unsigned short* offr_bf = value_bf + M256;
    unsigned short* core_bf = offr_bf + M256;
    unsigned short* x_bf    = core_bf + M256;
    unsigned short* attw_bf = x_bf + M256;               // M*128
    unsigned short* wcat    = attw_bf + (size_t)M * 128; // 640*256
    unsigned short* woutt   = wcat + 163840;             // 256*256
    unsigned short* w1t     = woutt + 65536;             // 1024*256
    unsigned short* w2t     = w1t + 262144;              // 256*1024
    // h aliases [src_bf, value, offr, core] (all dead before k_ffn1): M*1024
    unsigned short* h_bf    = w16;

    const int gb64 = (M + 63) / 64;
    const int ngrp = (nk + 63) / 64;

    k_cvt_all<<<4096, 256, 0, stream>>>(src, src_bf, M * 64,
                                        w_val, w_off, w_att, w_out, w1, w2,
                                        wcat, woutt, w1t, w2t);
    k_proj<<<dim3(gb64, 3), 512, 0, stream>>>(src_bf, wcat, b_val, b_off, b_att,
                                              value_bf, offr_bf, attw_bf, M, nk);
    k_sample<<<ngrp * 16, 256, 0, stream>>>(value_bf, offr_bf, attw_bf, ref,
                                            shapes, lsi, core_bf, M);
    k_oproj<<<gb64, 512, 0, stream>>>(core_bf, woutt, b_out, src, g1, bt1, x_bf, M);
    k_ffn1<<<dim3(gb64, 4), 512, 0, stream>>>(x_bf, w1t, b1, h_bf, M);
    k_ffn2<<<gb64, 512, 0, stream>>>(h_bf, w2t, b2, x_bf, g2, bt2,
                                     (float*)d_out, M);
}

// Round 16
// 256.236 us; speedup vs baseline: 1.0916x; 1.0017x over previous
//
#include <hip/hip_runtime.h>
#include <math.h>

#define EMBED 256
#define HEADS 8
#define LEVELS 4
#define POINTS 4
#define FFNDIM 1024

typedef float f32x4 __attribute__((ext_vector_type(4)));
typedef float f32x2 __attribute__((ext_vector_type(2)));
typedef __bf16 bf16x8 __attribute__((ext_vector_type(8)));

static __device__ __forceinline__ float4 ld4f(const float* p) {
    return *reinterpret_cast<const float4*>(p);
}
static __device__ __forceinline__ unsigned short f2bf(float f) {
    unsigned int u = __float_as_uint(f);
    unsigned int r = (u + 0x7fffu + ((u >> 16) & 1u)) >> 16;
    return (unsigned short)r;
}
static __device__ __forceinline__ float bf2f(unsigned short u) {
    return __uint_as_float((unsigned int)u << 16);
}
static __device__ __forceinline__ f32x2 pkfma(f32x2 a, f32x2 b, f32x2 c) {
#if __has_builtin(__builtin_elementwise_fma)
    return __builtin_elementwise_fma(a, b, c);
#else
    f32x2 r; r.x = fmaf(a.x, b.x, c.x); r.y = fmaf(a.y, b.y, c.y); return r;
#endif
}
// async global->LDS, 16B per lane. LDS dest = wave-uniform base + lane*16.
static __device__ __forceinline__
void gl_lds16(const unsigned short* g, unsigned short* l) {
    __builtin_amdgcn_global_load_lds(
        (const __attribute__((address_space(1))) unsigned int*)g,
        (__attribute__((address_space(3))) unsigned int*)l, 16, 0, 0);
}

// ---------------------------------------------------------------------------
// Combined conversion: src fp32->bf16 (vectorized) + weight transpose/convert.
// ---------------------------------------------------------------------------
__global__ __launch_bounds__(256)
void k_cvt_all(const float* __restrict__ src, unsigned short* __restrict__ dst,
               int n4,
               const float* __restrict__ wv, const float* __restrict__ wo,
               const float* __restrict__ wa, const float* __restrict__ wout,
               const float* __restrict__ w1, const float* __restrict__ w2,
               unsigned short* __restrict__ wcat, unsigned short* __restrict__ woutt,
               unsigned short* __restrict__ w1t, unsigned short* __restrict__ w2t)
{
    const int wtotal = 163840 + 65536 + 262144 + 262144;
    const int total = n4 + wtotal;
    for (int gid = blockIdx.x * 256 + threadIdx.x; gid < total; gid += gridDim.x * 256) {
        if (gid < n4) {
            float4 v = ld4f(src + (size_t)gid * 4);
            ushort4 o;
            o.x = f2bf(v.x); o.y = f2bf(v.y); o.z = f2bf(v.z); o.w = f2bf(v.w);
            *reinterpret_cast<ushort4*>(dst + (size_t)gid * 4) = o;
        } else {
            int local = gid - n4;
            float f; unsigned short* dp;
            if (local < 163840) {                       // wcat_t [640][256]
                int n = local >> 8, k = local & 255;
                if (n < 256)      f = wv[k * 256 + n];
                else if (n < 512) f = wo[k * 256 + (n - 256)];
                else              f = wa[k * 128 + (n - 512)];
                dp = wcat + local;
            } else if ((local -= 163840) < 65536) {     // wout_t [256][256]
                int n = local >> 8, k = local & 255;
                f = wout[k * 256 + n];
                dp = woutt + local;
            } else if ((local -= 65536) < 262144) {     // w1_t [1024][256]
                int n = local >> 8, k = local & 255;
                f = w1[k * 1024 + n];
                dp = w1t + local;
            } else {                                    // w2_t [256][1024]
                local -= 262144;
                int n = local >> 10, k = local & 1023;
                f = w2[k * 256 + n];
                dp = w2t + local;
            }
            *dp = f2bf(f);
        }
    }
}

// ===========================================================================
// Shared GEMM geometry: BM=64, BN=256, BK=64, 512 threads = 8 waves (2Mx4N).
// Staging via global_load_lds width=16 into LINEAR LDS; bank conflicts
// avoided by XOR-swizzling the 16B slot on BOTH global source and ds_read.
// ===========================================================================

#define GEMM_STAGE(Aptr, ASTR, Wptr, WSTR, kcexp)                              \
    {                                                                          \
        int row = (wid << 3) + (lane >> 3);                                    \
        int slot = (lane & 7) ^ (row & 7);                                     \
        gl_lds16(Aptr + (size_t)(m0 + row) * ASTR + (kcexp) * 64 + slot * 8,   \
                 a_s + (size_t)(wid << 3) * 64);                               \
    }                                                                          \
    _Pragma("unroll")                                                          \
    for (int rnd = 0; rnd < 4; ++rnd) {                                        \
        int row = (rnd << 6) + (wid << 3) + (lane >> 3);                       \
        int slot = (lane & 7) ^ (row & 7);                                     \
        gl_lds16(Wptr + (size_t)(n0 + row) * WSTR + (kcexp) * 64 + slot * 8,   \
                 w_s + (size_t)((rnd << 6) + (wid << 3)) * 64);                \
    }

#define GEMM_FRAGS_MFMA                                                        \
    {                                                                          \
        bf16x8 af[2][2], bfr[4][2];                                            \
        const int ksb = (lane >> 4);                                           \
        _Pragma("unroll")                                                      \
        for (int i = 0; i < 2; ++i) {                                          \
            int m = wm * 32 + i * 16 + cl;                                     \
            _Pragma("unroll")                                                  \
            for (int kk = 0; kk < 2; ++kk) {                                   \
                int phys = (kk * 4 + ksb) ^ (m & 7);                           \
                af[i][kk] = *reinterpret_cast<const bf16x8*>(                  \
                    a_s + m * 64 + phys * 8);                                  \
            }                                                                  \
        }                                                                      \
        _Pragma("unroll")                                                      \
        for (int j = 0; j < 4; ++j) {                                          \
            int n = wn * 64 + j * 16 + cl;                                     \
            _Pragma("unroll")                                                  \
            for (int kk = 0; kk < 2; ++kk) {                                   \
                int phys = (kk * 4 + ksb) ^ (n & 7);                           \
                bfr[j][kk] = *reinterpret_cast<const bf16x8*>(                 \
                    w_s + n * 64 + phys * 8);                                  \
            }                                                                  \
        }                                                                      \
        _Pragma("unroll")                                                      \
        for (int kk = 0; kk < 2; ++kk)                                         \
            _Pragma("unroll")                                                  \
            for (int i = 0; i < 2; ++i)                                        \
                _Pragma("unroll")                                              \
                for (int j = 0; j < 4; ++j)                                    \
                    acc[i][j] = __builtin_amdgcn_mfma_f32_16x16x32_bf16(       \
                        af[i][kk], bfr[j][kk], acc[i][j], 0, 0, 0);            \
    }

// ---------------------------------------------------------------------------
// Projection GEMM: [value|off|att](M,640) = src_bf(M,256) @ wcat_t^T + bias
// grid.y: 0=value(HEAD-MAJOR out: [(b*8+h)][nk][32]), 1=off, 2=att(softmax16).
// ---------------------------------------------------------------------------
__global__ __launch_bounds__(512)
void k_proj(const unsigned short* __restrict__ A, const unsigned short* __restrict__ Wt,
            const float* __restrict__ b_val, const float* __restrict__ b_off,
            const float* __restrict__ b_att,
            unsigned short* __restrict__ value, unsigned short* __restrict__ offr,
            unsigned short* __restrict__ attw, int M, int nk)
{
    __shared__ __align__(16) unsigned short smem[20480];  // 40 KB
    unsigned short* a_s = smem;                           // 64 x 64
    unsigned short* w_s = smem + 4096;                    // 256 x 64
    const int tid = threadIdx.x;
    const int m0 = blockIdx.x * 64;
    const int y = blockIdx.y;
    const int n0 = y * 256;
    const int lane = tid & 63, wid = tid >> 6;
    const int wm = wid >> 2, wn = wid & 3;
    const int cl = lane & 15, r4 = (lane >> 4) * 4;

    f32x4 acc[2][4] = {};

    for (int kc = 0; kc < 4; ++kc) {
        __syncthreads();
        GEMM_STAGE(A, 256, Wt, 256, kc)
        __syncthreads();
        GEMM_FRAGS_MFMA
    }

    if (y < 2) {
        const float* bias = (y == 0) ? b_val : b_off;
        __syncthreads();
        #pragma unroll
        for (int j = 0; j < 4; ++j) {
            int col = wn * 64 + j * 16 + cl;
            float bv = bias[col];
            #pragma unroll
            for (int i = 0; i < 2; ++i)
                #pragma unroll
                for (int r = 0; r < 4; ++r)
                    smem[(wm * 32 + i * 16 + r4 + r) * 264 + col] = f2bf(acc[i][j][r] + bv);
        }
        __syncthreads();
        if (y == 0) {
            // head-major value store: 64B chunk per (row, head)
            #pragma unroll
            for (int t = 0; t < 4; ++t) {
                int idx = tid + t * 512;
                int row = idx >> 5, cu = idx & 31;
                int grow = m0 + row;
                if (grow < M) {
                    int b = grow >= nk;
                    int pix = grow - (b ? nk : 0);
                    int hh = cu >> 2, ch = (cu & 3) * 8;
                    *reinterpret_cast<uint4*>(
                        value + ((size_t)(b * 8 + hh) * nk + pix) * 32 + ch) =
                        *reinterpret_cast<const uint4*>(smem + row * 264 + cu * 8);
                }
            }
        } else {
            #pragma unroll
            for (int t = 0; t < 4; ++t) {
                int idx = tid + t * 512;
                int row = idx >> 5, cu = idx & 31;
                int grow = m0 + row;
                if (grow < M)
                    *reinterpret_cast<uint4*>(offr + (size_t)grow * 256 + cu * 8) =
                        *reinterpret_cast<const uint4*>(smem + row * 264 + cu * 8);
            }
        }
    } else {
        if (wn < 2) {
            #pragma unroll
            for (int j = 0; j < 4; ++j) {
                int a = wn * 64 + j * 16 + cl;
                float bv = b_att[a];
                #pragma unroll
                for (int i = 0; i < 2; ++i) {
                    #pragma unroll
                    for (int r = 0; r < 4; ++r) {
                        float v = acc[i][j][r] + bv;
                        float mx = v;
                        mx = fmaxf(mx, __shfl_xor(mx, 1));
                        mx = fmaxf(mx, __shfl_xor(mx, 2));
                        mx = fmaxf(mx, __shfl_xor(mx, 4));
                        mx = fmaxf(mx, __shfl_xor(mx, 8));
                        float e = __expf(v - mx);
                        float s = e;
                        s += __shfl_xor(s, 1);
                        s += __shfl_xor(s, 2);
                        s += __shfl_xor(s, 4);
                        s += __shfl_xor(s, 8);
                        acc[i][j][r] = e / s;
                    }
                }
            }
        }
        __syncthreads();
        if (wn < 2) {
            #pragma unroll
            for (int j = 0; j < 4; ++j) {
                int a = wn * 64 + j * 16 + cl;
                #pragma unroll
                for (int i = 0; i < 2; ++i)
                    #pragma unroll
                    for (int r = 0; r < 4; ++r)
                        smem[(wm * 32 + i * 16 + r4 + r) * 136 + a] = f2bf(acc[i][j][r]);
            }
        }
        __syncthreads();
        #pragma unroll
        for (int t = 0; t < 2; ++t) {
            int idx = tid + t * 512;           // 0..1023
            int row = idx >> 4, cu = idx & 15;
            int grow = m0 + row;
            if (grow < M)
                *reinterpret_cast<uint4*>(attw + (size_t)grow * 128 + cu * 8) =
                    *reinterpret_cast<const uint4*>(smem + row * 136 + cu * 8);
        }
    }
}

// ---------------------------------------------------------------------------
// Deformable sampling, HEAD-PARTITIONED blocks for XCD L2 locality.
// blockIdx.x = grp*16 + bh. Hi-channel unpack skips the mask: junk low-16
// mantissa bits perturb by <2^-8 relative -- same scale as bf16 rounding.
// ---------------------------------------------------------------------------
__global__ __launch_bounds__(256)
void k_sample(const unsigned short* __restrict__ value,
              const unsigned short* __restrict__ offr,
              const unsigned short* __restrict__ attw,
              const float* __restrict__ ref,
              const int* __restrict__ shapes, const int* __restrict__ lsi,
              unsigned short* __restrict__ core, int M)
{
    __shared__ int2 iw_s[64][65];            // [corner q][token] (pad 65)
    const int tid = threadIdx.x;
    const int bh = blockIdx.x & 15;
    const int grp = blockIdx.x >> 4;
    const int b = bh >> 3, h = bh & 7;
    const int nk = lsi[3] + shapes[6] * shapes[7];
    const int tok0 = grp * 64;

    #pragma unroll
    for (int rnd = 0; rnd < 4; ++rnd) {
        const int lp = tid & 15;             // l*4+p
        const int tk = rnd * 16 + (tid >> 4);
        const int l = lp >> 2;
        const int pix0 = tok0 + tk;
        int2 out[4];
        if (pix0 < nk) {
            const int token = b * nk + pix0;
            const int Hl = shapes[l * 2], Wl = shapes[l * 2 + 1];
            const int pbase = bh * nk + lsi[l];
            const float rx = ref[(size_t)token * 8 + l * 2];
            const float ry = ref[(size_t)token * 8 + l * 2 + 1];
            const unsigned int oxy = *reinterpret_cast<const unsigned int*>(
                offr + (size_t)token * 256 + (h * 16 + lp) * 2);
            const float ox = bf2f((unsigned short)(oxy & 0xffffu));
            const float oy = bf2f((unsigned short)(oxy >> 16));
            const float aw = bf2f(attw[(size_t)token * 128 + h * 16 + lp]);
            const float x = fmaf(rx, (float)Wl, ox) - 0.5f;
            const float y = fmaf(ry, (float)Hl, oy) - 0.5f;
            const float x0f = floorf(x), y0f = floorf(y);
            const float fx = x - x0f, fy = y - y0f;
            const int x0 = (int)x0f, y0 = (int)y0f;
            #pragma unroll
            for (int t = 0; t < 4; ++t) {
                const int dx = t & 1, dy = t >> 1;
                const int xi = x0 + dx, yi = y0 + dy;
                const bool valid = (xi >= 0) & (xi < Wl) & (yi >= 0) & (yi < Hl);
                const float w = (dx ? fx : 1.f - fx) * (dy ? fy : 1.f - fy) * aw;
                const int xc = min(max(xi, 0), Wl - 1);
                const int yc = min(max(yi, 0), Hl - 1);
                out[t].x = (pbase + yc * Wl + xc) * 16;   // u32 chunk offset
                out[t].y = __float_as_int(valid ? w : 0.f);
            }
        } else {
            #pragma unroll
            for (int t = 0; t < 4; ++t) out[t] = make_int2(0, 0);
        }
        #pragma unroll
        for (int t = 0; t < 4; ++t)
            iw_s[lp * 4 + t][tk] = out[t];
    }
    __syncthreads();

    const int tk = tid >> 2;
    const int dp = tid & 3;                  // channel oct: ch 8dp..8dp+7
    const int pix = tok0 + tk;
    const unsigned int* vu = reinterpret_cast<const unsigned int*>(value) + dp * 4;
    f32x2 a0 = {0.f, 0.f}, a1 = {0.f, 0.f};
    f32x2 a2 = {0.f, 0.f}, a3 = {0.f, 0.f};
    #pragma unroll 16
    for (int q = 0; q < 64; ++q) {
        const int2 iw = iw_s[q][tk];
        const float w = __int_as_float(iw.y);
        const f32x2 w2 = {w, w};
        const uint4 v = *reinterpret_cast<const uint4*>(vu + (size_t)(unsigned)iw.x);
        // lo = u<<16 (exact); hi = u unmasked (junk mantissa, <2^-8 rel err)
        const f32x2 v0 = {__uint_as_float(v.x << 16), __uint_as_float(v.x)};
        const f32x2 v1 = {__uint_as_float(v.y << 16), __uint_as_float(v.y)};
        const f32x2 v2 = {__uint_as_float(v.z << 16), __uint_as_float(v.z)};
        const f32x2 v3 = {__uint_as_float(v.w << 16), __uint_as_float(v.w)};
        a0 = pkfma(v0, w2, a0);
        a1 = pkfma(v1, w2, a1);
        a2 = pkfma(v2, w2, a2);
        a3 = pkfma(v3, w2, a3);
    }
    if (pix < nk) {
        uint4 o;
        o.x = (unsigned int)f2bf(a0.x) | ((unsigned int)f2bf(a0.y) << 16);
        o.y = (unsigned int)f2bf(a1.x) | ((unsigned int)f2bf(a1.y) << 16);
        o.z = (unsigned int)f2bf(a2.x) | ((unsigned int)f2bf(a2.y) << 16);
        o.w = (unsigned int)f2bf(a3.x) | ((unsigned int)f2bf(a3.y) << 16);
        *reinterpret_cast<uint4*>(
            core + (size_t)(b * nk + pix) * 256 + h * 32 + dp * 8) = o;
    }
}

// ---------------------------------------------------------------------------
// Out-projection + residual + LN1: x_bf = LN(src + core_bf @ wout + b_out)
// ---------------------------------------------------------------------------
__global__ __launch_bounds__(512)
void k_oproj(const unsigned short* __restrict__ A, const unsigned short* __restrict__ Wt,
             const float* __restrict__ b_out, const float* __restrict__ src,
             const float* __restrict__ g1, const float* __restrict__ bt1,
             unsigned short* __restrict__ X, int M)
{
    __shared__ __align__(16) unsigned short smem[20480];
    unsigned short* a_s = smem;
    unsigned short* w_s = smem + 4096;
    __shared__ float red[64 * 8];
    __shared__ float mr[64 * 2];
    const int tid = threadIdx.x;
    const int m0 = blockIdx.x * 64;
    const int n0 = 0;
    const int lane = tid & 63, wid = tid >> 6;
    const int wm = wid >> 2, wn = wid & 3;
    const int cl = lane & 15, r4 = (lane >> 4) * 4;

    f32x4 acc[2][4] = {};

    for (int kc = 0; kc < 4; ++kc) {
        __syncthreads();
        GEMM_STAGE(A, 256, Wt, 256, kc)
        __syncthreads();
        GEMM_FRAGS_MFMA
    }

    #pragma unroll
    for (int j = 0; j < 4; ++j) {
        int col = wn * 64 + j * 16 + cl;
        float bv = b_out[col];
        #pragma unroll
        for (int i = 0; i < 2; ++i) {
            int mb = wm * 32 + i * 16 + r4;
            #pragma unroll
            for (int r = 0; r < 4; ++r) {
                int row = m0 + mb + r;
                float sv = (row < M) ? src[(size_t)row * 256 + col] : 0.f;
                acc[i][j][r] += bv + sv;
            }
        }
    }
    #pragma unroll
    for (int i = 0; i < 2; ++i)
        #pragma unroll
        for (int r = 0; r < 4; ++r) {
            float s1 = 0.f, s2 = 0.f;
            #pragma unroll
            for (int j = 0; j < 4; ++j) { float t = acc[i][j][r]; s1 += t; s2 += t * t; }
            s1 += __shfl_xor(s1, 1); s2 += __shfl_xor(s2, 1);
            s1 += __shfl_xor(s1, 2); s2 += __shfl_xor(s2, 2);
            s1 += __shfl_xor(s1, 4); s2 += __shfl_xor(s2, 4);
            s1 += __shfl_xor(s1, 8); s2 += __shfl_xor(s2, 8);
            if (cl == 0) {
                int rr = wm * 32 + i * 16 + r4 + r;
                red[(rr * 4 + wn) * 2 + 0] = s1;
                red[(rr * 4 + wn) * 2 + 1] = s2;
            }
        }
    __syncthreads();
    if (tid < 64) {
        float s1 = red[tid * 8] + red[tid * 8 + 2] + red[tid * 8 + 4] + red[tid * 8 + 6];
        float s2 = red[tid * 8 + 1] + red[tid * 8 + 3] + red[tid * 8 + 5] + red[tid * 8 + 7];
        float mu = s1 * (1.f / 256.f);
        mr[tid * 2] = mu;
        mr[tid * 2 + 1] = rsqrtf(fmaxf(s2 * (1.f / 256.f) - mu * mu, 0.f) + 1e-5f);
    }
    __syncthreads();
    #pragma unroll
    for (int j = 0; j < 4; ++j) {
        int col = wn * 64 + j * 16 + cl;
        float gv = g1[col], bt = bt1[col];
        #pragma unroll
        for (int i = 0; i < 2; ++i)
            #pragma unroll
            for (int r = 0; r < 4; ++r) {
                int rr = wm * 32 + i * 16 + r4 + r;
                smem[rr * 264 + col] =
                    f2bf((acc[i][j][r] - mr[rr * 2]) * mr[rr * 2 + 1] * gv + bt);
            }
    }
    __syncthreads();
    #pragma unroll
    for (int t = 0; t < 4; ++t) {
        int idx = tid + t * 512;
        int row = idx >> 5, cu = idx & 31;
        int grow = m0 + row;
        if (grow < M)
            *reinterpret_cast<uint4*>(X + (size_t)grow * 256 + cu * 8) =
                *reinterpret_cast<const uint4*>(smem + row * 264 + cu * 8);
    }
}

// ---------------------------------------------------------------------------
// FFN GEMM1: h(M,1024) = relu(x_bf @ W1t^T + b1). grid.y = 256-col slab.
// ---------------------------------------------------------------------------
__global__ __launch_bounds__(512)
void k_ffn1(const unsigned short* __restrict__ A, const unsigned short* __restrict__ W1t,
            const float* __restrict__ B1, unsigned short* __restrict__ h, int M)
{
    __shared__ __align__(16) unsigned short smem[20480];
    unsigned short* a_s = smem;
    unsigned short* w_s = smem + 4096;
    const int tid = threadIdx.x;
    const int m0 = blockIdx.x * 64;
    const int n0 = blockIdx.y * 256;
    const int lane = tid & 63, wid = tid >> 6;
    const int wm = wid >> 2, wn = wid & 3;
    const int cl = lane & 15, r4 = (lane >> 4) * 4;

    f32x4 acc[2][4] = {};

    for (int kc = 0; kc < 4; ++kc) {
        __syncthreads();
        GEMM_STAGE(A, 256, W1t, 256, kc)
        __syncthreads();
        GEMM_FRAGS_MFMA
    }

    __syncthreads();
    #pragma unroll
    for (int j = 0; j < 4; ++j) {
        int col = wn * 64 + j * 16 + cl;
        float bv = B1[n0 + col];
        #pragma unroll
        for (int i = 0; i < 2; ++i)
            #pragma unroll
            for (int r = 0; r < 4; ++r)
                smem[(wm * 32 + i * 16 + r4 + r) * 264 + col] =
                    f2bf(fmaxf(acc[i][j][r] + bv, 0.f));
    }
    __syncthreads();
    #pragma unroll
    for (int t = 0; t < 4; ++t) {
        int idx = tid + t * 512;
        int row = idx >> 5, cu = idx & 31;
        int grow = m0 + row;
        if (grow < M)
            *reinterpret_cast<uint4*>(h + (size_t)grow * 1024 + n0 + cu * 8) =
                *reinterpret_cast<const uint4*>(smem + row * 264 + cu * 8);
    }
}

// ---------------------------------------------------------------------------
// FFN GEMM2 + residual + LN2: out = LN(x_bf + h @ W2t^T + b2), fp32 out.
// K=1024 (16 kc steps).
// ---------------------------------------------------------------------------
__global__ __launch_bounds__(512)
void k_ffn2(const unsigned short* __restrict__ h, const unsigned short* __restrict__ W2t,
            const float* __restrict__ B2, const unsigned short* __restrict__ Xbf,
            const float* __restrict__ G2, const float* __restrict__ BT2,
            float* __restrict__ OUT, int M)
{
    __shared__ __align__(16) unsigned short smem[20480];
    unsigned short* a_s = smem;
    unsigned short* w_s = smem + 4096;
    __shared__ float red[64 * 8];
    __shared__ float mr[64 * 2];
    const int tid = threadIdx.x;
    const int m0 = blockIdx.x * 64;
    const int n0 = 0;
    const int lane = tid & 63, wid = tid >> 6;
    const int wm = wid >> 2, wn = wid & 3;
    const int cl = lane & 15, r4 = (lane >> 4) * 4;

    f32x4 acc[2][4] = {};

    for (int kc = 0; kc < 16; ++kc) {
        __syncthreads();
        GEMM_STAGE(h, 1024, W2t, 1024, kc)
        __syncthreads();
        GEMM_FRAGS_MFMA
    }

    // epilogue: v = acc + b2 + x (bf16 residual); LN2; fp32 out
    #pragma unroll
    for (int j = 0; j < 4; ++j) {
        int col = wn * 64 + j * 16 + cl;
        float bv = B2[col];
        #pragma unroll
        for (int i = 0; i < 2; ++i) {
            int mb = wm * 32 + i * 16 + r4;
            #pragma unroll
            for (int r = 0; r < 4; ++r) {
                int row = m0 + mb + r;
                float xv = (row < M) ? bf2f(Xbf[(size_t)row * 256 + col]) : 0.f;
                acc[i][j][r] += bv + xv;
            }
        }
    }
    #pragma unroll
    for (int i = 0; i < 2; ++i)
        #pragma unroll
        for (int r = 0; r < 4; ++r) {
            float s1 = 0.f, s2 = 0.f;
            #pragma unroll
            for (int j = 0; j < 4; ++j) { float t = acc[i][j][r]; s1 += t; s2 += t * t; }
            s1 += __shfl_xor(s1, 1); s2 += __shfl_xor(s2, 1);
            s1 += __shfl_xor(s1, 2); s2 += __shfl_xor(s2, 2);
            s1 += __shfl_xor(s1, 4); s2 += __shfl_xor(s2, 4);
            s1 += __shfl_xor(s1, 8); s2 += __shfl_xor(s2, 8);
            if (cl == 0) {
                int rr = wm * 32 + i * 16 + r4 + r;
                red[(rr * 4 + wn) * 2 + 0] = s1;
                red[(rr * 4 + wn) * 2 + 1] = s2;
            }
        }
    __syncthreads();
    if (tid < 64) {
        float s1 = red[tid * 8] + red[tid * 8 + 2] + red[tid * 8 + 4] + red[tid * 8 + 6];
        float s2 = red[tid * 8 + 1] + red[tid * 8 + 3] + red[tid * 8 + 5] + red[tid * 8 + 7];
        float mu = s1 * (1.f / 256.f);
        mr[tid * 2] = mu;
        mr[tid * 2 + 1] = rsqrtf(fmaxf(s2 * (1.f / 256.f) - mu * mu, 0.f) + 1e-5f);
    }
    __syncthreads();
    #pragma unroll
    for (int j = 0; j < 4; ++j) {
        int col = wn * 64 + j * 16 + cl;
        float gv = G2[col], bt = BT2[col];
        #pragma unroll
        for (int i = 0; i < 2; ++i) {
            int mb = wm * 32 + i * 16 + r4;
            #pragma unroll
            for (int r = 0; r < 4; ++r) {
                int rr = mb + r, row = m0 + rr;
                if (row < M)
                    OUT[(size_t)row * 256 + col] =
                        (acc[i][j][r] - mr[rr * 2]) * mr[rr * 2 + 1] * gv + bt;
            }
        }
    }
}

// ---------------------------------------------------------------------------
extern "C" void kernel_launch(void* const* d_in, const int* in_sizes, int n_in,
                              void* d_out, int out_size, void* d_ws, size_t ws_size,
                              hipStream_t stream) {
    const float* src    = (const float*)d_in[0];
    const float* ref    = (const float*)d_in[1];
    const int*   shapes = (const int*)d_in[2];
    const int*   lsi    = (const int*)d_in[3];
    const float* b_off  = (const float*)d_in[5];
    const float* b_att  = (const float*)d_in[7];
    const float* b_val  = (const float*)d_in[9];
    const float* b_out  = (const float*)d_in[11];
    const float* g1     = (const float*)d_in[12];
    const float* bt1    = (const float*)d_in[13];
    const float* b1     = (const float*)d_in[15];
    const float* b2     = (const float*)d_in[17];
    const float* g2     = (const float*)d_in[18];
    const float* bt2    = (const float*)d_in[19];
    const float* w_off  = (const float*)d_in[4];
    const float* w_att  = (const float*)d_in[6];
    const float* w_val  = (const float*)d_in[8];
    const float* w_out  = (const float*)d_in[10];
    const float* w1     = (const float*)d_in[14];
    const float* w2     = (const float*)d_in[16];

    const int M = in_sizes[0] / EMBED;  // B*nq = 49130
    const int nk = M / 2;               // B == 2
    const size_t M256 = (size_t)M * 256;

    unsigned short* w16     = (unsigned short*)d_ws;
    unsigned short* src_bf  = w16;
    unsigned short* value_bf = src_bf + M256;
    unsigned short* offr_bf = value_bf + M256;
    unsigned short* core_bf = offr_bf + M256;
    unsigned short* x_bf    = core_bf + M256;
    unsigned short* attw_bf = x_bf + M256;               // M*128
    unsigned short* wcat    = attw_bf + (size_t)M * 128; // 640*256
    unsigned short* woutt   = wcat + 163840;             // 256*256
    unsigned short* w1t     = woutt + 65536;             // 1024*256
    unsigned short* w2t     = w1t + 262144;              // 256*1024
    // h aliases [src_bf, value, offr, core] (all dead before k_ffn1): M*1024
    unsigned short* h_bf    = w16;

    const int gb64 = (M + 63) / 64;
    const int ngrp = (nk + 63) / 64;

    k_cvt_all<<<4096, 256, 0, stream>>>(src, src_bf, M * 64,
                                        w_val, w_off, w_att, w_out, w1, w2,
                                        wcat, woutt, w1t, w2t);
    k_proj<<<dim3(gb64, 3), 512, 0, stream>>>(src_bf, wcat, b_val, b_off, b_att,
                                              value_bf, offr_bf, attw_bf, M, nk);
    k_sample<<<ngrp * 16, 256, 0, stream>>>(value_bf, offr_bf, attw_bf, ref,
                                            shapes, lsi, core_bf, M);
    k_oproj<<<gb64, 512, 0, stream>>>(core_bf, woutt, b_out, src, g1, bt1, x_bf, M);
    k_ffn1<<<dim3(gb64, 4), 512, 0, stream>>>(x_bf, w1t, b1, h_bf, M);
    k_ffn2<<<gb64, 512, 0, stream>>>(h_bf, w2t, b2, x_bf, g2, bt2,
                                     (float*)d_out, M);
}